// Round 1
// baseline (2315.867 us; speedup 1.0000x reference)
//
#include <hip/hip_runtime.h>
#include <hip/hip_bf16.h>

#define BB 64
#define TT 256
#define EE 128
#define HH 256
#define LL 9
#define FOURH 1024

typedef __bf16 bf16x8 __attribute__((ext_vector_type(8)));
typedef float  f32x4  __attribute__((ext_vector_type(4)));

// ---------------- helpers ----------------
__device__ __forceinline__ float sigf(float x){
    return __fdividef(1.f, 1.f + __expf(-x));
}
__device__ __forceinline__ float tanh_f(float x){
    float ax = fabsf(x);
    float e  = __expf(-2.f * ax);
    float t  = (1.f - e) * __fdividef(1.f, 1.f + e);
    return copysignf(t, x);
}

// ---------------- lens ----------------
__global__ __launch_bounds__(256) void k_lens(const int* __restrict__ ch,
                                              int* __restrict__ lens_i,
                                              float* __restrict__ out_lens){
    int b = blockIdx.x, t = threadIdx.x;
    __shared__ int cnt;
    if (t == 0) cnt = 0;
    __syncthreads();
    int v = (ch[(b << 8) + t] != 0) ? 1 : 0;
    unsigned long long bal = __ballot(v);
    if ((t & 63) == 0) atomicAdd(&cnt, __popcll(bal));
    __syncthreads();
    if (t == 0){ lens_i[b] = cnt; out_lens[b] = (float)cnt; }
}

// ---------------- x = char_emb[char] + word_emb[word] @ W_word ----------------
__global__ __launch_bounds__(256) void k_x(const int* __restrict__ ch, const int* __restrict__ wd,
                                           const float* __restrict__ cemb, const float* __restrict__ wemb,
                                           const float* __restrict__ Ww, float* __restrict__ x){
    int tok = blockIdx.x * 2 + (threadIdx.x >> 7);
    int e   = threadIdx.x & 127;
    int c = ch[tok], w = wd[tok];
    float acc = cemb[c * EE + e];
    const float* wrow = wemb + w * 100;
    #pragma unroll 4
    for (int k = 0; k < 100; ++k)
        acc = fmaf(wrow[k], Ww[k * EE + e], acc);
    x[tok * EE + e] = acc;
}

// ---------------- persistent BiLSTM ----------------
// 32 WGs: dir = wg>>4 (0 fwd, 1 bwd), slice = wg&15 owns hidden dims [slice*16, slice*16+16)
// Per step: z(64x64) = [x_t ; h_prev](64x384) @ Wslice(384x64), 3-term bf16 MFMA, fp32 acc.
__global__ __launch_bounds__(256, 1) void k_lstm(
        const float* __restrict__ x,
        const float* __restrict__ Wi_f, const float* __restrict__ Wh_f, const float* __restrict__ b_f,
        const float* __restrict__ Wi_b, const float* __restrict__ Wh_b, const float* __restrict__ b_b,
        float* __restrict__ hf, float* __restrict__ hb,
        unsigned long long* __restrict__ ctrs){
    const int wg    = blockIdx.x;
    const int dir   = wg >> 4;
    const int slice = wg & 15;
    const int tid   = threadIdx.x;
    const int wave  = tid >> 6, lane = tid & 63;

    const float* Wi   = dir ? Wi_b : Wi_f;
    const float* Wh   = dir ? Wh_b : Wh_f;
    const float* bias = dir ? b_b  : b_f;
    float* hdst       = dir ? hb   : hf;
    const float* hsrc = hdst;
    unsigned long long* ctr = ctrs + dir * 16;   // 128B apart

    __shared__ __align__(16) __bf16 Whi[4][12][64][8];
    __shared__ __align__(16) __bf16 Wlo[4][12][64][8];

    // stage W slice (packed per MFMA fragment, hi/lo split)
    for (int idx = tid; idx < 4 * 12 * 64 * 8; idx += 256){
        int j = idx & 7, ln = (idx >> 3) & 63, rest = idx >> 9;
        int kc = rest % 12, nt = rest / 12;
        int k = kc * 32 + ((ln >> 4) << 3) + j;
        int c = (nt << 8) + (slice << 4) + (ln & 15);
        float w = (k < EE) ? Wi[k * FOURH + c] : Wh[(k - EE) * FOURH + c];
        __bf16 h = (__bf16)w;
        Whi[nt][kc][ln][j] = h;
        Wlo[nt][kc][ln][j] = (__bf16)(w - (float)h);
    }
    float bv[4];
    #pragma unroll
    for (int nt = 0; nt < 4; ++nt)
        bv[nt] = bias[(nt << 8) + (slice << 4) + (lane & 15)];
    __syncthreads();

    const int arow  = (wave << 4) + (lane & 15);   // A-operand batch row
    const int glane = lane >> 4;
    const int brow0 = (wave << 4) + (glane << 2);  // C/D base batch row
    const int dcol  = (slice << 4) + (lane & 15);  // hidden dim
    float cst[4] = {0.f, 0.f, 0.f, 0.f};

    for (int s = 0; s < TT; ++s){
        const int t  = dir ? (TT - 1 - s) : s;
        const int tp = dir ? (t + 1) : (t - 1);
        f32x4 acc[4] = {{0,0,0,0},{0,0,0,0},{0,0,0,0},{0,0,0,0}};
        const int kcend = s ? 12 : 4;   // first step has no h
        for (int kc = 0; kc < kcend; ++kc){
            float4 v0, v1;
            if (kc < 4){
                const float* ap = x + ((((arow << 8) + t) << 7) + (kc << 5) + (glane << 3));
                v0 = *(const float4*)ap; v1 = *(const float4*)(ap + 4);
            } else {
                const float* ap = hsrc + ((((arow << 8) + tp) << 8) + ((kc - 4) << 5) + (glane << 3));
                v0 = *(const float4*)ap; v1 = *(const float4*)(ap + 4);
            }
            float av[8] = {v0.x, v0.y, v0.z, v0.w, v1.x, v1.y, v1.z, v1.w};
            bf16x8 ahi, alo;
            #pragma unroll
            for (int j = 0; j < 8; ++j){
                __bf16 hh = (__bf16)av[j];
                ahi[j] = hh;
                alo[j] = (__bf16)(av[j] - (float)hh);
            }
            #pragma unroll
            for (int nt = 0; nt < 4; ++nt){
                bf16x8 bh = *(const bf16x8*)&Whi[nt][kc][lane][0];
                bf16x8 bl = *(const bf16x8*)&Wlo[nt][kc][lane][0];
                acc[nt] = __builtin_amdgcn_mfma_f32_16x16x32_bf16(ahi, bh, acc[nt], 0, 0, 0);
                acc[nt] = __builtin_amdgcn_mfma_f32_16x16x32_bf16(ahi, bl, acc[nt], 0, 0, 0);
                acc[nt] = __builtin_amdgcn_mfma_f32_16x16x32_bf16(alo, bh, acc[nt], 0, 0, 0);
            }
        }
        #pragma unroll
        for (int r = 0; r < 4; ++r){
            float zi = acc[0][r] + bv[0];
            float zf = acc[1][r] + bv[1];
            float zg = acc[2][r] + bv[2];
            float zo = acc[3][r] + bv[3];
            float cn = sigf(zf) * cst[r] + sigf(zi) * tanh_f(zg);
            float hn = sigf(zo) * tanh_f(cn);
            cst[r] = cn;
            hdst[((((brow0 + r) << 8) + t) << 8) + dcol] = hn;
        }
        // per-direction grid barrier (release add, acquire spin)
        __syncthreads();
        if (tid == 0){
            __hip_atomic_fetch_add(ctr, 1ull, __ATOMIC_RELEASE, __HIP_MEMORY_SCOPE_AGENT);
            unsigned long long tgt = 16ull * (unsigned long long)(s + 1);
            while (__hip_atomic_load(ctr, __ATOMIC_ACQUIRE, __HIP_MEMORY_SCOPE_AGENT) < tgt)
                __builtin_amdgcn_s_sleep(4);
        }
        __syncthreads();
    }
}

// ---------------- logits = [hf|hb] @ W_out + b_out ----------------
__global__ __launch_bounds__(256) void k_logits(const float* __restrict__ hf, const float* __restrict__ hb,
                                                const float* __restrict__ Wo, const float* __restrict__ bo,
                                                float* __restrict__ out){
    __shared__ float hs[32][513];
    __shared__ float wsm[512 * 9];
    __shared__ float bs[9];
    int tid = threadIdx.x, wg = blockIdx.x;
    for (int idx = tid; idx < 512 * 9; idx += 256) wsm[idx] = Wo[idx];
    if (tid < 9) bs[tid] = bo[tid];
    for (int idx = tid; idx < 32 * 512; idx += 256){
        int r = idx >> 9, k = idx & 511;
        int row = (wg << 5) + r;
        hs[r][k] = (k < HH) ? hf[(row << 8) + k] : hb[(row << 8) + (k - HH)];
    }
    __syncthreads();
    for (int pos = tid; pos < 32 * 9; pos += 256){
        int r = pos / 9, l = pos - r * 9;
        float acc = bs[l];
        #pragma unroll 8
        for (int k = 0; k < 512; ++k)
            acc = fmaf(hs[r][k], wsm[k * 9 + l], acc);
        out[((wg << 5) + r) * 9 + l] = acc;
    }
}

// ---------------- CRF: score, log-norm, viterbi, backtrace ----------------
__global__ __launch_bounds__(128) void k_crf(const float* __restrict__ logits, const int* __restrict__ labels,
                                             const float* __restrict__ trans, const int* __restrict__ lens_i,
                                             float* __restrict__ out_ll, float* __restrict__ out_tags){
    int b = blockIdx.x, tid = threadIdx.x;
    __shared__ float lg[TT * LL];
    __shared__ float tr[81];
    __shared__ unsigned char bp[255 * LL];
    __shared__ float aF[LL], aV[LL];
    __shared__ float red[2];
    __shared__ float score_s, lognorm_s;
    __shared__ int tagb[TT];

    const float* lgg = logits + b * TT * LL;
    for (int idx = tid; idx < TT * LL; idx += 128) lg[idx] = lgg[idx];
    if (tid < 81) tr[tid] = trans[tid];
    __syncthreads();
    const int len = lens_i[b];
    const int* lab = labels + (b << 8);

    // gold score
    float local = 0.f;
    for (int t = tid; t < TT; t += 128){
        if (t < len){
            int lt = lab[t];
            local += lg[t * LL + lt];
            if (t >= 1) local += tr[lab[t - 1] * LL + lt];
        }
    }
    #pragma unroll
    for (int o = 32; o; o >>= 1) local += __shfl_down(local, o);
    if ((tid & 63) == 0) red[tid >> 6] = local;
    __syncthreads();
    if (tid == 0) score_s = red[0] + red[1];

    if (tid < 64){
        // wave 0: forward log-norm recursion (lanes 0..8 active)
        int col = (tid < LL) ? tid : (LL - 1);
        float a = lg[col];
        for (int t = 1; t < TT; ++t){
            float ai[LL];
            #pragma unroll
            for (int i = 0; i < LL; ++i) ai[i] = __shfl(a, i);
            float m = -1e30f;
            #pragma unroll
            for (int i = 0; i < LL; ++i) m = fmaxf(m, ai[i] + tr[i * LL + col]);
            float ssum = 0.f;
            #pragma unroll
            for (int i = 0; i < LL; ++i) ssum += __expf(ai[i] + tr[i * LL + col] - m);
            float nv = m + __logf(ssum) + lg[t * LL + col];
            if (t < len) a = nv;
        }
        if (tid < LL) aF[tid] = a;
    } else {
        // wave 1: viterbi
        int lane = tid - 64;
        int col = (lane < LL) ? lane : (LL - 1);
        float v = lg[col];
        for (int t = 1; t < TT; ++t){
            float vi[LL];
            #pragma unroll
            for (int i = 0; i < LL; ++i) vi[i] = __shfl(v, i);
            float best = -1e30f; int barg = 0;
            #pragma unroll
            for (int i = 0; i < LL; ++i){
                float sc = vi[i] + tr[i * LL + col];
                if (sc > best){ best = sc; barg = i; }
            }
            float nv = best + lg[t * LL + col];
            bool keep = (t < len);
            if (lane < LL) bp[(t - 1) * LL + lane] = (unsigned char)(keep ? barg : lane);
            if (keep) v = nv;
        }
        if (lane < LL) aV[lane] = v;
    }
    __syncthreads();

    if (tid == 0){
        float m = aF[0];
        #pragma unroll
        for (int i = 1; i < LL; ++i) m = fmaxf(m, aF[i]);
        float s = 0.f;
        #pragma unroll
        for (int i = 0; i < LL; ++i) s += __expf(aF[i] - m);
        lognorm_s = m + __logf(s);

        float bv2 = aV[0]; int last = 0;
        #pragma unroll
        for (int i = 1; i < LL; ++i) if (aV[i] > bv2){ bv2 = aV[i]; last = i; }
        int tag = last; tagb[TT - 1] = last;
        for (int k = TT - 2; k >= 0; --k){ tag = bp[k * LL + tag]; tagb[k] = tag; }
        out_ll[b] = score_s - lognorm_s;
    }
    __syncthreads();
    for (int t = tid; t < TT; t += 128) out_tags[(b << 8) + t] = (float)tagb[t];
}

// ---------------- launcher ----------------
extern "C" void kernel_launch(void* const* d_in, const int* in_sizes, int n_in,
                              void* d_out, int out_size, void* d_ws, size_t ws_size,
                              hipStream_t stream){
    const int*   ch    = (const int*)  d_in[0];
    const int*   wd    = (const int*)  d_in[1];
    const int*   lab   = (const int*)  d_in[2];
    const float* cemb  = (const float*)d_in[3];
    const float* wemb  = (const float*)d_in[4];
    const float* Ww    = (const float*)d_in[5];
    const float* Wi_f  = (const float*)d_in[6];
    const float* Wh_f  = (const float*)d_in[7];
    const float* b_f   = (const float*)d_in[8];
    const float* Wi_b  = (const float*)d_in[9];
    const float* Wh_b  = (const float*)d_in[10];
    const float* b_b   = (const float*)d_in[11];
    const float* Wo    = (const float*)d_in[12];
    const float* bo    = (const float*)d_in[13];
    const float* trans = (const float*)d_in[14];

    float* out = (float*)d_out;
    float* out_logits = out;                       // 64*256*9 = 147456
    float* out_lens   = out + 147456;              // 64
    float* out_ll     = out + 147520;              // 64
    float* out_tags   = out + 147584;              // 64*256

    float* wsf = (float*)d_ws;
    unsigned long long* ctrs = (unsigned long long*)d_ws;       // [0,256) bytes
    int*   lens_i = (int*)((char*)d_ws + 256);                  // 64 ints
    float* x  = wsf + 1024;                                     // B*T*E
    float* hf = x  + (size_t)BB * TT * EE;                      // B*T*H
    float* hb = hf + (size_t)BB * TT * HH;

    hipMemsetAsync(d_ws, 0, 512, stream);
    k_lens  <<<BB, 256, 0, stream>>>(ch, lens_i, out_lens);
    k_x     <<<(BB * TT) / 2, 256, 0, stream>>>(ch, wd, cemb, wemb, Ww, x);
    k_lstm  <<<32, 256, 0, stream>>>(x, Wi_f, Wh_f, b_f, Wi_b, Wh_b, b_b, hf, hb, ctrs);
    k_logits<<<(BB * TT) / 32, 256, 0, stream>>>(hf, hb, Wo, bo, out_logits);
    k_crf   <<<BB, 128, 0, stream>>>(out_logits, lab, trans, lens_i, out_ll, out_tags);
}

// Round 7
// 1915.912 us; speedup vs baseline: 1.2088x; 1.2088x over previous
//
#include <hip/hip_runtime.h>
#include <hip/hip_bf16.h>

#define BB 64
#define TT 256
#define EE 128
#define HH 256
#define LL 9

typedef __bf16 bf16x8 __attribute__((ext_vector_type(8)));
typedef unsigned short u16x8 __attribute__((ext_vector_type(8)));
typedef float  f32x4  __attribute__((ext_vector_type(4)));

union U8  { u16x8 u; bf16x8 b; };
union Q8  { uint4 q; bf16x8 b; };

#define H_ALL(dir,s,row,dim) ((((((dir)<<8)+(s))<<6)+(row))*256+(dim))
#define XPK(t,row,k)         ((((t)*64+(row))<<7)+(k))

// ---------------- helpers ----------------
__device__ __forceinline__ float sigf(float x){
    return __fdividef(1.f, 1.f + __expf(-x));
}
__device__ __forceinline__ float tanh_f(float x){
    float ax = fabsf(x);
    float e  = __expf(-2.f * ax);
    float t  = (1.f - e) * __fdividef(1.f, 1.f + e);
    return copysignf(t, x);
}
__device__ __forceinline__ void unpack8(uint4 a, uint4 b, bf16x8& hi, bf16x8& lo){
    unsigned int w[8] = {a.x, a.y, a.z, a.w, b.x, b.y, b.z, b.w};
    U8 h, l;
    #pragma unroll
    for (int j = 0; j < 8; ++j){
        h.u[j] = (unsigned short)(w[j] >> 16);
        l.u[j] = (unsigned short)(w[j] & 0xffffu);
    }
    hi = h.b; lo = l.b;
}

// ---------------- lens ----------------
__global__ __launch_bounds__(256) void k_lens(const int* __restrict__ ch,
                                              int* __restrict__ lens_i,
                                              float* __restrict__ out_lens){
    int b = blockIdx.x, t = threadIdx.x;
    __shared__ int cnt;
    if (t == 0) cnt = 0;
    __syncthreads();
    int v = (ch[(b << 8) + t] != 0) ? 1 : 0;
    unsigned long long bal = __ballot(v);
    if ((t & 63) == 0) atomicAdd(&cnt, __popcll(bal));
    __syncthreads();
    if (t == 0){ lens_i[b] = cnt; out_lens[b] = (float)cnt; }
}

// ---------------- x = char_emb[char] + word_emb[word] @ W_word, bf16 (hi only) ----------------
__global__ __launch_bounds__(256) void k_x(const int* __restrict__ ch, const int* __restrict__ wd,
                                           const float* __restrict__ cemb, const float* __restrict__ wemb,
                                           const float* __restrict__ Ww, unsigned short* __restrict__ xpack){
    int tok = blockIdx.x * 2 + (threadIdx.x >> 7);
    int e   = threadIdx.x & 127;
    int b = tok >> 8, t = tok & 255;
    int c = ch[tok], w = wd[tok];
    float acc = cemb[c * EE + e];
    const float* wrow = wemb + w * 100;
    #pragma unroll 4
    for (int k = 0; k < 100; ++k)
        acc = fmaf(wrow[k], Ww[k * EE + e], acc);
    xpack[XPK(t, b, e)] = __builtin_bit_cast(unsigned short, (__bf16)acc);
}

// ---------------- weight pack: frag layout, hi/lo split ----------------
__global__ __launch_bounds__(256) void k_wpack(const float* __restrict__ Wi_f, const float* __restrict__ Wh_f,
                                               const float* __restrict__ Wi_b, const float* __restrict__ Wh_b,
                                               unsigned short* __restrict__ Whip, unsigned short* __restrict__ Wlop){
    int blk = blockIdx.x;
    int dir = blk / 96; int rem = blk - dir * 96;
    int ns = rem / 12;  int kc  = rem - ns * 12;
    const float* Wi = dir ? Wi_b : Wi_f;
    const float* Wh = dir ? Wh_b : Wh_f;
    __shared__ float raw[32][128];   // [kk][g*32 + cc]
    int tid = threadIdx.x;
    for (int e = tid; e < 4096; e += 256){
        int kk = e >> 7, rest = e & 127, g = rest >> 5, cc = rest & 31;
        int k = kc * 32 + kk;
        int c = g * 256 + ns * 32 + cc;
        raw[kk][rest] = (k < EE) ? Wi[k * 1024 + c] : Wh[(k - EE) * 1024 + c];
    }
    __syncthreads();
    for (int f = tid; f < 512; f += 256){
        int ntL = f >> 6, ln = f & 63;
        int c16 = ln & 15, khi = ln >> 4;
        int w = ntL >> 1;
        int g = (c16 >> 3) + ((ntL & 1) << 1);
        int dd = c16 & 7;
        int col = g * 32 + w * 8 + dd;
        unsigned short hibuf[8], lobuf[8];
        #pragma unroll
        for (int j = 0; j < 8; ++j){
            float v = raw[khi * 8 + j][col];
            __bf16 h = (__bf16)v;
            __bf16 l = (__bf16)(v - (float)h);
            hibuf[j] = __builtin_bit_cast(unsigned short, h);
            lobuf[j] = __builtin_bit_cast(unsigned short, l);
        }
        size_t base = ((((size_t)(dir * 8 + ns) * 12 + kc) * 8 + ntL) * 64 + ln) * 8;
        *(uint4*)&Whip[base] = *(uint4*)hibuf;
        *(uint4*)&Wlop[base] = *(uint4*)lobuf;
    }
}

// ---------------- BiLSTM: 64 WGs = dir(2) x bg(4) x ns(8); M=16, N=128, K=384 ----------------
// Cross-WG exchange entirely at the device coherent point (MALL):
//   publish  = atomicExch (RMW, relaxed)   -> lands at MALL
//   signal   = s_waitcnt vmcnt(0); relaxed atomicAdd
//   consume  = relaxed poll; relaxed ATOMIC u64 loads (bypass stale private L2)
// No buffer_inv / buffer_wbl2 is ever emitted (no acquire/release used).
__global__ __launch_bounds__(256, 1) void k_lstm(
        const float* __restrict__ b_f, const float* __restrict__ b_b,
        const unsigned short* __restrict__ Whip, const unsigned short* __restrict__ Wlop,
        const unsigned short* __restrict__ xpack,
        unsigned int* __restrict__ h_all,
        unsigned int* __restrict__ ctrs){
    const int wg  = blockIdx.x;
    const int dir = wg >> 5;
    const int bg  = (wg >> 3) & 3;
    const int ns  = wg & 7;
    const int tid  = threadIdx.x;
    const int wave = tid >> 6;
    const int lane = tid & 63;
    const int c16  = lane & 15;
    const int l4   = lane >> 4;
    const int sw   = c16 & 7;

    __shared__ __align__(16) unsigned short Whi[12 * 8 * 64 * 8];   // 96 KB
    __shared__ __align__(16) unsigned int hstage[2][16 * 256];      // 32 KB
    __shared__ __align__(16) unsigned short xstage[2][16 * 128];    //  8 KB

    // one-time: stage Whi slice (96 KB) to LDS
    const unsigned short* wsrc = Whip + (size_t)((dir * 8 + ns) * 12) * 8 * 64 * 8;
    for (int idx = tid * 8; idx < 12 * 8 * 64 * 8; idx += 256 * 8)
        *(uint4*)&Whi[idx] = *(const uint4*)&wsrc[idx];

    const float* bias = dir ? b_b : b_f;
    const int dd   = c16 & 7;
    const int gA   = c16 >> 3;                       // 0/1
    const int dimG = (ns << 5) + (wave << 3) + dd;   // hidden dim [0,256)
    const float biasA = bias[gA * 256 + dimG];
    const float biasB = bias[(2 + gA) * 256 + dimG];
    const bool  ga0   = (c16 & 8) == 0;

    unsigned int* ctr = ctrs + (dir * 4 + bg) * 32;  // 128B spacing
    const unsigned short* wlo = Wlop + (size_t)((dir * 8 + ns) * 12) * 8 * 64 * 8;
    const int ntA = wave * 2, ntB = ntA + 1;

    float cst[4] = {0.f, 0.f, 0.f, 0.f};

    const int lrow = tid >> 4;            // staging row [0,16)
    const int rs   = lrow & 7;
    const int grow = bg * 16 + lrow;      // global batch row for staging

    for (int s = 0; s < TT; ++s){
        const int t = dir ? (TT - 1 - s) : s;
        const int p = s & 1;

        // A) x loads for this step (plain loads: xpack written by a prior kernel)
        const unsigned short* xsrc = xpack + XPK(t, grow, (tid & 15) << 3);
        uint4 x0 = *(const uint4*)xsrc;

        // B) spin until group peers posted h(s-1)  (relaxed: no cache maintenance)
        if (s > 0){
            unsigned int tgt = 32u * (unsigned)s;
            while (__hip_atomic_load(ctr, __ATOMIC_RELAXED, __HIP_MEMORY_SCOPE_AGENT) < tgt)
                __builtin_amdgcn_s_sleep(2);
        }
        asm volatile("" ::: "memory");

        // C) h loads as relaxed agent-scope ATOMIC u64 loads -> served at MALL,
        //    immune to stale private-L2 lines
        unsigned long long hv64[8];
        if (s > 0){
            const unsigned long long* hsrc =
                (const unsigned long long*)(h_all + H_ALL(dir, s - 1, grow, (tid & 15) << 4));
            #pragma unroll
            for (int j = 0; j < 8; ++j)
                hv64[j] = __hip_atomic_load(hsrc + j, __ATOMIC_RELAXED, __HIP_MEMORY_SCOPE_AGENT);
        }

        // D) swizzled LDS staging (16B-chunk granularity XOR swizzle)
        {
            uint4* xrow = (uint4*)&xstage[p][lrow * 128];
            int kch = tid & 15;
            xrow[kch ^ rs] = x0;
            if (s > 0){
                uint4* hrow = (uint4*)&hstage[p][lrow * 256];
                int gch = (tid & 15) << 2;
                uint4 q0, q1, q2, q3;
                q0.x = (unsigned)hv64[0]; q0.y = (unsigned)(hv64[0] >> 32);
                q0.z = (unsigned)hv64[1]; q0.w = (unsigned)(hv64[1] >> 32);
                q1.x = (unsigned)hv64[2]; q1.y = (unsigned)(hv64[2] >> 32);
                q1.z = (unsigned)hv64[3]; q1.w = (unsigned)(hv64[3] >> 32);
                q2.x = (unsigned)hv64[4]; q2.y = (unsigned)(hv64[4] >> 32);
                q2.z = (unsigned)hv64[5]; q2.w = (unsigned)(hv64[5] >> 32);
                q3.x = (unsigned)hv64[6]; q3.y = (unsigned)(hv64[6] >> 32);
                q3.z = (unsigned)hv64[7]; q3.w = (unsigned)(hv64[7] >> 32);
                hrow[(gch    ) ^ rs] = q0;
                hrow[(gch + 1) ^ rs] = q1;
                hrow[(gch + 2) ^ rs] = q2;
                hrow[(gch + 3) ^ rs] = q3;
            }
        }
        __syncthreads();

        // F) MFMA: z(16 x 128) = [x ; h] @ Wslice; x part 2-term, h part 3-term hi/lo
        f32x4 accA = {0.f, 0.f, 0.f, 0.f};
        f32x4 accB = {0.f, 0.f, 0.f, 0.f};
        const int kcend = s ? 12 : 4;
        Q8 wloA_c, wloB_c, wloA_n, wloB_n;
        wloA_c.q = *(const uint4*)&wlo[((0 * 8 + ntA) * 64 + lane) * 8];
        wloB_c.q = *(const uint4*)&wlo[((0 * 8 + ntB) * 64 + lane) * 8];
        for (int kc = 0; kc < kcend; ++kc){
            if (kc + 1 < kcend){
                wloA_n.q = *(const uint4*)&wlo[(((kc + 1) * 8 + ntA) * 64 + lane) * 8];
                wloB_n.q = *(const uint4*)&wlo[(((kc + 1) * 8 + ntB) * 64 + lane) * 8];
            }
            bf16x8 bhA = *(const bf16x8*)&Whi[((kc * 8 + ntA) * 64 + lane) * 8];
            bf16x8 bhB = *(const bf16x8*)&Whi[((kc * 8 + ntB) * 64 + lane) * 8];
            if (kc < 4){
                const uint4* xr = (const uint4*)&xstage[p][c16 * 128];
                Q8 ax; ax.q = xr[(kc * 4 + l4) ^ sw];
                accA = __builtin_amdgcn_mfma_f32_16x16x32_bf16(ax.b, bhA,      accA, 0, 0, 0);
                accA = __builtin_amdgcn_mfma_f32_16x16x32_bf16(ax.b, wloA_c.b, accA, 0, 0, 0);
                accB = __builtin_amdgcn_mfma_f32_16x16x32_bf16(ax.b, bhB,      accB, 0, 0, 0);
                accB = __builtin_amdgcn_mfma_f32_16x16x32_bf16(ax.b, wloB_c.b, accB, 0, 0, 0);
            } else {
                const uint4* hr = (const uint4*)&hstage[p][c16 * 256];
                int g0 = (kc - 4) * 8 + l4 * 2;
                uint4 a0 = hr[(g0    ) ^ sw];
                uint4 a1 = hr[(g0 + 1) ^ sw];
                bf16x8 ahi, alo;
                unpack8(a0, a1, ahi, alo);
                accA = __builtin_amdgcn_mfma_f32_16x16x32_bf16(ahi, bhA,      accA, 0, 0, 0);
                accA = __builtin_amdgcn_mfma_f32_16x16x32_bf16(ahi, wloA_c.b, accA, 0, 0, 0);
                accA = __builtin_amdgcn_mfma_f32_16x16x32_bf16(alo, bhA,      accA, 0, 0, 0);
                accB = __builtin_amdgcn_mfma_f32_16x16x32_bf16(ahi, bhB,      accB, 0, 0, 0);
                accB = __builtin_amdgcn_mfma_f32_16x16x32_bf16(ahi, wloB_c.b, accB, 0, 0, 0);
                accB = __builtin_amdgcn_mfma_f32_16x16x32_bf16(alo, bhB,      accB, 0, 0, 0);
            }
            wloA_c = wloA_n; wloB_c = wloB_n;
        }

        // G/H) activations + publish h (RMW write-through to MALL)
        #pragma unroll
        for (int r = 0; r < 4; ++r){
            float zA = accA[r] + biasA;
            float zB = accB[r] + biasB;
            float oA = __shfl_xor(zA, 8);
            float oB = __shfl_xor(zB, 8);
            float zi = ga0 ? zA : oA;
            float zf = ga0 ? oA : zA;
            float zg = ga0 ? zB : oB;
            float zo = ga0 ? oB : zB;
            float cn = sigf(zf) * cst[r] + sigf(zi) * tanh_f(zg);
            float hn = sigf(zo) * tanh_f(cn);
            cst[r] = cn;
            if (ga0){
                __bf16 hh = (__bf16)hn;
                __bf16 hl = (__bf16)(hn - (float)hh);
                unsigned int pk = (((unsigned int)__builtin_bit_cast(unsigned short, hh)) << 16)
                                | (unsigned int)__builtin_bit_cast(unsigned short, hl);
                int row = bg * 16 + l4 * 4 + r;
                (void)__hip_atomic_exchange(&h_all[H_ALL(dir, s, row, dimG)], pk,
                                            __ATOMIC_RELAXED, __HIP_MEMORY_SCOPE_AGENT);
            }
        }
        // I) signal: own RMWs retired at the coherent point, then per-wave relaxed add
        asm volatile("s_waitcnt vmcnt(0)" ::: "memory");
        if (lane == 0)
            (void)__hip_atomic_fetch_add(ctr, 1u, __ATOMIC_RELAXED, __HIP_MEMORY_SCOPE_AGENT);
    }
}

// ---------------- logits = [hf|hb] @ W_out + b_out ----------------
__global__ __launch_bounds__(256) void k_logits(const unsigned int* __restrict__ h_all,
                                                const float* __restrict__ Wo, const float* __restrict__ bo,
                                                float* __restrict__ out){
    __shared__ float hs[32][513];
    __shared__ float wsm[512 * 9];
    __shared__ float bs[9];
    int tid = threadIdx.x, wgid = blockIdx.x;
    int b = wgid >> 3, t0 = (wgid & 7) * 32;
    for (int idx = tid; idx < 512 * 9; idx += 256) wsm[idx] = Wo[idx];
    if (tid < 9) bs[tid] = bo[tid];
    for (int idx = tid; idx < 32 * 512; idx += 256){
        int r = idx >> 9, k = idx & 511;
        int t = t0 + r;
        unsigned int pk = (k < HH) ? h_all[H_ALL(0, t, b, k)]
                                   : h_all[H_ALL(1, 255 - t, b, k - HH)];
        float hi = __builtin_bit_cast(float, (pk >> 16) << 16);
        float lo = __builtin_bit_cast(float, (pk & 0xffffu) << 16);
        hs[r][k] = hi + lo;
    }
    __syncthreads();
    for (int pos = tid; pos < 32 * 9; pos += 256){
        int r = pos / 9, l = pos - r * 9;
        float acc = bs[l];
        #pragma unroll 8
        for (int k = 0; k < 512; ++k)
            acc = fmaf(hs[r][k], wsm[k * 9 + l], acc);
        out[(b * 256 + t0 + r) * 9 + l] = acc;
    }
}

// ---------------- CRF: score, log-norm, viterbi, backtrace ----------------
__global__ __launch_bounds__(128) void k_crf(const float* __restrict__ logits, const int* __restrict__ labels,
                                             const float* __restrict__ trans, const int* __restrict__ lens_i,
                                             float* __restrict__ out_ll, float* __restrict__ out_tags){
    int b = blockIdx.x, tid = threadIdx.x;
    __shared__ float lg[TT * LL];
    __shared__ float tr[81];
    __shared__ unsigned char bp[255 * LL];
    __shared__ float aF[LL], aV[LL];
    __shared__ float red[2];
    __shared__ float score_s;
    __shared__ int tagb[TT];

    const float* lgg = logits + b * TT * LL;
    for (int idx = tid; idx < TT * LL; idx += 128) lg[idx] = lgg[idx];
    if (tid < 81) tr[tid] = trans[tid];
    __syncthreads();
    const int len = lens_i[b];
    const int* lab = labels + (b << 8);

    float local = 0.f;
    for (int t = tid; t < TT; t += 128){
        if (t < len){
            int lt = lab[t];
            local += lg[t * LL + lt];
            if (t >= 1) local += tr[lab[t - 1] * LL + lt];
        }
    }
    #pragma unroll
    for (int o = 32; o; o >>= 1) local += __shfl_down(local, o);
    if ((tid & 63) == 0) red[tid >> 6] = local;
    __syncthreads();
    if (tid == 0) score_s = red[0] + red[1];

    if (tid < 64){
        int col = (tid < LL) ? tid : (LL - 1);
        float a = lg[col];
        for (int t = 1; t < TT; ++t){
            float ai[LL];
            #pragma unroll
            for (int i = 0; i < LL; ++i) ai[i] = __shfl(a, i);
            float m = -1e30f;
            #pragma unroll
            for (int i = 0; i < LL; ++i) m = fmaxf(m, ai[i] + tr[i * LL + col]);
            float ssum = 0.f;
            #pragma unroll
            for (int i = 0; i < LL; ++i) ssum += __expf(ai[i] + tr[i * LL + col] - m);
            float nv = m + __logf(ssum) + lg[t * LL + col];
            if (t < len) a = nv;
        }
        if (tid < LL) aF[tid] = a;
    } else {
        int lane = tid - 64;
        int col = (lane < LL) ? lane : (LL - 1);
        float v = lg[col];
        for (int t = 1; t < TT; ++t){
            float vi[LL];
            #pragma unroll
            for (int i = 0; i < LL; ++i) vi[i] = __shfl(v, i);
            float best = -1e30f; int barg = 0;
            #pragma unroll
            for (int i = 0; i < LL; ++i){
                float sc = vi[i] + tr[i * LL + col];
                if (sc > best){ best = sc; barg = i; }
            }
            float nv = best + lg[t * LL + col];
            bool keep = (t < len);
            if (lane < LL) bp[(t - 1) * LL + lane] = (unsigned char)(keep ? barg : lane);
            if (keep) v = nv;
        }
        if (lane < LL) aV[lane] = v;
    }
    __syncthreads();

    if (tid == 0){
        float m = aF[0];
        #pragma unroll
        for (int i = 1; i < LL; ++i) m = fmaxf(m, aF[i]);
        float ssum = 0.f;
        #pragma unroll
        for (int i = 0; i < LL; ++i) ssum += __expf(aF[i] - m);
        float lognorm = m + __logf(ssum);

        float bv2 = aV[0]; int last = 0;
        #pragma unroll
        for (int i = 1; i < LL; ++i) if (aV[i] > bv2){ bv2 = aV[i]; last = i; }
        int tag = last; tagb[TT - 1] = last;
        for (int k = TT - 2; k >= 0; --k){ tag = bp[k * LL + tag]; tagb[k] = tag; }
        out_ll[b] = score_s - lognorm;
    }
    __syncthreads();
    for (int t = tid; t < TT; t += 128) out_tags[(b << 8) + t] = (float)tagb[t];
}

// ---------------- launcher ----------------
extern "C" void kernel_launch(void* const* d_in, const int* in_sizes, int n_in,
                              void* d_out, int out_size, void* d_ws, size_t ws_size,
                              hipStream_t stream){
    const int*   ch    = (const int*)  d_in[0];
    const int*   wd    = (const int*)  d_in[1];
    const int*   lab   = (const int*)  d_in[2];
    const float* cemb  = (const float*)d_in[3];
    const float* wemb  = (const float*)d_in[4];
    const float* Ww    = (const float*)d_in[5];
    const float* Wi_f  = (const float*)d_in[6];
    const float* Wh_f  = (const float*)d_in[7];
    const float* b_f   = (const float*)d_in[8];
    const float* Wi_b  = (const float*)d_in[9];
    const float* Wh_b  = (const float*)d_in[10];
    const float* b_b   = (const float*)d_in[11];
    const float* Wo    = (const float*)d_in[12];
    const float* bo    = (const float*)d_in[13];
    const float* trans = (const float*)d_in[14];

    float* out = (float*)d_out;
    float* out_logits = out;               // 64*256*9
    float* out_lens   = out + 147456;      // 64
    float* out_ll     = out + 147520;      // 64
    float* out_tags   = out + 147584;      // 64*256

    // workspace layout (total 40,898,560 B -- below round-1-proven 41,947,136 B)
    char* ws = (char*)d_ws;
    unsigned int*   ctrs   = (unsigned int*)ws;                                  // 1 KB
    int*            lens_i = (int*)(ws + 2048);                                  // 256 B
    unsigned int*   h_all  = (unsigned int*)(ws + 4096);                         // 32 MB
    unsigned short* xpack  = (unsigned short*)(ws + 4096 + 33554432);            // 4 MB
    unsigned short* Whip   = (unsigned short*)(ws + 4096 + 33554432 + 4194304);  // 1.5 MB
    unsigned short* Wlop   = (unsigned short*)(ws + 4096 + 33554432 + 4194304 + 1572864); // 1.5 MB

    hipMemsetAsync(d_ws, 0, 2048, stream);
    k_lens  <<<BB, 256, 0, stream>>>(ch, lens_i, out_lens);
    k_wpack <<<192, 256, 0, stream>>>(Wi_f, Wh_f, Wi_b, Wh_b, Whip, Wlop);
    k_x     <<<(BB * TT) / 2, 256, 0, stream>>>(ch, wd, cemb, wemb, Ww, xpack);
    k_lstm  <<<64, 256, 0, stream>>>(b_f, b_b, Whip, Wlop, xpack, h_all, ctrs);
    k_logits<<<(BB * TT) / 32, 256, 0, stream>>>(h_all, Wo, bo, out_logits);
    k_crf   <<<BB, 128, 0, stream>>>(out_logits, lab, trans, lens_i, out_ll, out_tags);
}

// Round 8
// 1291.951 us; speedup vs baseline: 1.7925x; 1.4830x over previous
//
#include <hip/hip_runtime.h>
#include <hip/hip_bf16.h>

#define BB 64
#define TT 256
#define EE 128
#define HH 256
#define LL 9

typedef __bf16 bf16x8 __attribute__((ext_vector_type(8)));
typedef unsigned short u16x8 __attribute__((ext_vector_type(8)));
typedef float  f32x4  __attribute__((ext_vector_type(4)));
typedef unsigned int u32x4 __attribute__((ext_vector_type(4)));

union U8  { u16x8 u; bf16x8 b; };
union Q8  { u32x4 q; bf16x8 b; };

#define H_ALL(dir,s,row,dim) ((((((dir)<<8)+(s))<<6)+(row))*256+(dim))
#define XPK(t,row,k)         ((((t)*64+(row))<<7)+(k))

// ---------------- helpers ----------------
__device__ __forceinline__ float sigf(float x){
    return __fdividef(1.f, 1.f + __expf(-x));
}
__device__ __forceinline__ float tanh_f(float x){
    float ax = fabsf(x);
    float e  = __expf(-2.f * ax);
    float t  = (1.f - e) * __fdividef(1.f, 1.f + e);
    return copysignf(t, x);
}
__device__ __forceinline__ void unpack8(u32x4 a, u32x4 b, bf16x8& hi, bf16x8& lo){
    unsigned int w[8] = {a[0], a[1], a[2], a[3], b[0], b[1], b[2], b[3]};
    U8 h, l;
    #pragma unroll
    for (int j = 0; j < 8; ++j){
        h.u[j] = (unsigned short)(w[j] >> 16);
        l.u[j] = (unsigned short)(w[j] & 0xffffu);
    }
    hi = h.b; lo = l.b;
}

// ---------------- lens ----------------
__global__ __launch_bounds__(256) void k_lens(const int* __restrict__ ch,
                                              int* __restrict__ lens_i,
                                              float* __restrict__ out_lens){
    int b = blockIdx.x, t = threadIdx.x;
    __shared__ int cnt;
    if (t == 0) cnt = 0;
    __syncthreads();
    int v = (ch[(b << 8) + t] != 0) ? 1 : 0;
    unsigned long long bal = __ballot(v);
    if ((t & 63) == 0) atomicAdd(&cnt, __popcll(bal));
    __syncthreads();
    if (t == 0){ lens_i[b] = cnt; out_lens[b] = (float)cnt; }
}

// ---------------- x = char_emb[char] + word_emb[word] @ W_word, bf16 (hi only) ----------------
__global__ __launch_bounds__(256) void k_x(const int* __restrict__ ch, const int* __restrict__ wd,
                                           const float* __restrict__ cemb, const float* __restrict__ wemb,
                                           const float* __restrict__ Ww, unsigned short* __restrict__ xpack){
    int tok = blockIdx.x * 2 + (threadIdx.x >> 7);
    int e   = threadIdx.x & 127;
    int b = tok >> 8, t = tok & 255;
    int c = ch[tok], w = wd[tok];
    float acc = cemb[c * EE + e];
    const float* wrow = wemb + w * 100;
    #pragma unroll 4
    for (int k = 0; k < 100; ++k)
        acc = fmaf(wrow[k], Ww[k * EE + e], acc);
    xpack[XPK(t, b, e)] = __builtin_bit_cast(unsigned short, (__bf16)acc);
}

// ---------------- weight pack: frag layout, hi/lo split ----------------
__global__ __launch_bounds__(256) void k_wpack(const float* __restrict__ Wi_f, const float* __restrict__ Wh_f,
                                               const float* __restrict__ Wi_b, const float* __restrict__ Wh_b,
                                               unsigned short* __restrict__ Whip, unsigned short* __restrict__ Wlop){
    int blk = blockIdx.x;
    int dir = blk / 96; int rem = blk - dir * 96;
    int ns = rem / 12;  int kc  = rem - ns * 12;
    const float* Wi = dir ? Wi_b : Wi_f;
    const float* Wh = dir ? Wh_b : Wh_f;
    __shared__ float raw[32][128];   // [kk][g*32 + cc]
    int tid = threadIdx.x;
    for (int e = tid; e < 4096; e += 256){
        int kk = e >> 7, rest = e & 127, g = rest >> 5, cc = rest & 31;
        int k = kc * 32 + kk;
        int c = g * 256 + ns * 32 + cc;
        raw[kk][rest] = (k < EE) ? Wi[k * 1024 + c] : Wh[(k - EE) * 1024 + c];
    }
    __syncthreads();
    for (int f = tid; f < 512; f += 256){
        int ntL = f >> 6, ln = f & 63;
        int c16 = ln & 15, khi = ln >> 4;
        int w = ntL >> 1;
        int g = (c16 >> 3) + ((ntL & 1) << 1);
        int dd = c16 & 7;
        int col = g * 32 + w * 8 + dd;
        unsigned short hibuf[8], lobuf[8];
        #pragma unroll
        for (int j = 0; j < 8; ++j){
            float v = raw[khi * 8 + j][col];
            __bf16 h = (__bf16)v;
            __bf16 l = (__bf16)(v - (float)h);
            hibuf[j] = __builtin_bit_cast(unsigned short, h);
            lobuf[j] = __builtin_bit_cast(unsigned short, l);
        }
        size_t base = ((((size_t)(dir * 8 + ns) * 12 + kc) * 8 + ntL) * 64 + ln) * 8;
        *(uint4*)&Whip[base] = *(uint4*)hibuf;
        *(uint4*)&Wlop[base] = *(uint4*)lobuf;
    }
}

// ---------------- BiLSTM: 64 WGs = dir(2) x bg(4) x ns(8); M=16, N=128, K=384 ----------------
// Exchange at the device coherent point; NO per-lane atomic storms:
//   publish  = atomicExch (RMW, relaxed)       -> lands at MALL   [unchanged, HW-proven]
//   signal   = s_waitcnt vmcnt(0); lane0 relaxed atomicAdd (4/WG)
//   poll     = tid==0 ONLY (1 uncached load per WG per iteration), then __syncthreads
//   h read   = global_load_dwordx4 sc1 (device-scope, coalesced, bypasses stale L2)
// W-lo fragments hoisted to registers BEFORE the poll (latency hidden under wait).
__global__ __launch_bounds__(256, 1) void k_lstm(
        const float* __restrict__ b_f, const float* __restrict__ b_b,
        const unsigned short* __restrict__ Whip, const unsigned short* __restrict__ Wlop,
        const unsigned short* __restrict__ xpack,
        unsigned int* __restrict__ h_all,
        unsigned int* __restrict__ ctrs){
    const int wg  = blockIdx.x;
    const int dir = wg >> 5;
    const int bg  = (wg >> 3) & 3;
    const int ns  = wg & 7;
    const int tid  = threadIdx.x;
    const int wave = tid >> 6;
    const int lane = tid & 63;
    const int c16  = lane & 15;
    const int l4   = lane >> 4;
    const int sw   = c16 & 7;

    __shared__ __align__(16) unsigned short Whi[12 * 8 * 64 * 8];   // 96 KB
    __shared__ __align__(16) unsigned int hstage[2][16 * 256];      // 32 KB
    __shared__ __align__(16) unsigned short xstage[2][16 * 128];    //  8 KB

    // one-time: stage Whi slice (96 KB) to LDS
    const unsigned short* wsrc = Whip + (size_t)((dir * 8 + ns) * 12) * 8 * 64 * 8;
    for (int idx = tid * 8; idx < 12 * 8 * 64 * 8; idx += 256 * 8)
        *(uint4*)&Whi[idx] = *(const uint4*)&wsrc[idx];

    const float* bias = dir ? b_b : b_f;
    const int gA   = c16 >> 3;                       // 0/1
    const int dd   = c16 & 7;
    const int dimG = (ns << 5) + (wave << 3) + dd;   // hidden dim [0,256)
    const float biasA = bias[gA * 256 + dimG];
    const float biasB = bias[(2 + gA) * 256 + dimG];
    const bool  ga0   = (c16 & 8) == 0;

    unsigned int* ctr = ctrs + (dir * 4 + bg) * 32;  // 128B spacing
    const unsigned short* wlo = Wlop + (size_t)((dir * 8 + ns) * 12) * 8 * 64 * 8;
    const int ntA = wave * 2, ntB = ntA + 1;

    float cst[4] = {0.f, 0.f, 0.f, 0.f};

    const int lrow = tid >> 4;            // staging row [0,16)
    const int rs   = lrow & 7;
    const int grow = bg * 16 + lrow;      // global batch row for staging
    const int cch  = tid & 15;            // staging chunk id

    for (int s = 0; s < TT; ++s){
        const int t = dir ? (TT - 1 - s) : s;
        const int p = s & 1;

        // A) hoisted loads, all issued BEFORE the poll (latency hides under wait):
        //    x for this step + the full W-lo fragment set (24 x 16B -> registers)
        const unsigned short* xsrc = xpack + XPK(t, grow, cch << 3);
        uint4 x0 = *(const uint4*)xsrc;
        u32x4 wloR[12][2];
        #pragma unroll
        for (int kc = 0; kc < 12; ++kc){
            wloR[kc][0] = *(const u32x4*)&wlo[((kc * 8 + ntA) * 64 + lane) * 8];
            wloR[kc][1] = *(const u32x4*)&wlo[((kc * 8 + ntB) * 64 + lane) * 8];
        }

        // B) poll by tid 0 ONLY (kills the same-address poll storm), then barrier
        if (s > 0){
            if (tid == 0){
                unsigned int tgt = 32u * (unsigned)s;
                while (__hip_atomic_load(ctr, __ATOMIC_RELAXED, __HIP_MEMORY_SCOPE_AGENT) < tgt)
                    __builtin_amdgcn_s_sleep(1);
            }
            __syncthreads();
        }

        // C) h read: coalesced device-scope (sc1) dwordx4 loads served at the
        //    coherent point -- no per-lane atomic serialization, no stale L2.
        //    thread (lrow, cch) loads dims {4c..4c+4}+{64,128,192} of row grow.
        u32x4 q0, q1, q2, q3;
        if (s > 0){
            const unsigned int* hbase = h_all + H_ALL(dir, s - 1, grow, cch << 2);
            asm volatile(
                "global_load_dwordx4 %0, %4, off sc1\n\t"
                "global_load_dwordx4 %1, %4, off offset:256 sc1\n\t"
                "global_load_dwordx4 %2, %4, off offset:512 sc1\n\t"
                "global_load_dwordx4 %3, %4, off offset:768 sc1\n\t"
                "s_waitcnt vmcnt(0)"
                : "=&v"(q0), "=&v"(q1), "=&v"(q2), "=&v"(q3)
                : "v"(hbase)
                : "memory");
        }

        // D) swizzled LDS staging; stride-16 chunk assignment (2-way banks, was 8-way)
        {
            *(uint4*)&xstage[p][lrow * 128 + ((cch ^ rs) << 3)] = x0;
            if (s > 0){
                u32x4* hrow = (u32x4*)&hstage[p][lrow * 256];
                int base = cch ^ rs;        // (cch+16q)^rs == (cch^rs)+16q  (rs<8)
                hrow[base     ] = q0;
                hrow[base + 16] = q1;
                hrow[base + 32] = q2;
                hrow[base + 48] = q3;
            }
        }
        __syncthreads();

        // F) MFMA: z(16x128) = [x ; h] @ Wslice; x-part 2-term, h-part 3-term hi/lo.
        //    Split accumulators (even/odd kc) halve the dependent MFMA chain.
        f32x4 accA0 = {0,0,0,0}, accA1 = {0,0,0,0};
        f32x4 accB0 = {0,0,0,0}, accB1 = {0,0,0,0};
        #pragma unroll
        for (int kc = 0; kc < 4; ++kc){
            bf16x8 bhA = *(const bf16x8*)&Whi[((kc * 8 + ntA) * 64 + lane) * 8];
            bf16x8 bhB = *(const bf16x8*)&Whi[((kc * 8 + ntB) * 64 + lane) * 8];
            const uint4* xr = (const uint4*)&xstage[p][c16 * 128];
            Q8 ax; ax.q = *(const u32x4*)&xr[(kc * 4 + l4) ^ sw];
            Q8 wA; wA.q = wloR[kc][0];
            Q8 wB; wB.q = wloR[kc][1];
            f32x4& aA = (kc & 1) ? accA1 : accA0;
            f32x4& aB = (kc & 1) ? accB1 : accB0;
            aA = __builtin_amdgcn_mfma_f32_16x16x32_bf16(ax.b, bhA,  aA, 0, 0, 0);
            aA = __builtin_amdgcn_mfma_f32_16x16x32_bf16(ax.b, wA.b, aA, 0, 0, 0);
            aB = __builtin_amdgcn_mfma_f32_16x16x32_bf16(ax.b, bhB,  aB, 0, 0, 0);
            aB = __builtin_amdgcn_mfma_f32_16x16x32_bf16(ax.b, wB.b, aB, 0, 0, 0);
        }
        if (s > 0){
            #pragma unroll
            for (int kc = 4; kc < 12; ++kc){
                bf16x8 bhA = *(const bf16x8*)&Whi[((kc * 8 + ntA) * 64 + lane) * 8];
                bf16x8 bhB = *(const bf16x8*)&Whi[((kc * 8 + ntB) * 64 + lane) * 8];
                const u32x4* hr = (const u32x4*)&hstage[p][c16 * 256];
                int g0 = (kc - 4) * 8 + l4 * 2;
                u32x4 a0 = hr[(g0    ) ^ sw];
                u32x4 a1 = hr[(g0 + 1) ^ sw];
                bf16x8 ahi, alo;
                unpack8(a0, a1, ahi, alo);
                Q8 wA; wA.q = wloR[kc][0];
                Q8 wB; wB.q = wloR[kc][1];
                f32x4& aA = (kc & 1) ? accA1 : accA0;
                f32x4& aB = (kc & 1) ? accB1 : accB0;
                aA = __builtin_amdgcn_mfma_f32_16x16x32_bf16(ahi, bhA,  aA, 0, 0, 0);
                aA = __builtin_amdgcn_mfma_f32_16x16x32_bf16(ahi, wA.b, aA, 0, 0, 0);
                aA = __builtin_amdgcn_mfma_f32_16x16x32_bf16(alo, bhA,  aA, 0, 0, 0);
                aB = __builtin_amdgcn_mfma_f32_16x16x32_bf16(ahi, bhB,  aB, 0, 0, 0);
                aB = __builtin_amdgcn_mfma_f32_16x16x32_bf16(ahi, wB.b, aB, 0, 0, 0);
                aB = __builtin_amdgcn_mfma_f32_16x16x32_bf16(alo, bhB,  aB, 0, 0, 0);
            }
        }

        // G/H) activations + publish h (RMW write-through to MALL) [unchanged]
        #pragma unroll
        for (int r = 0; r < 4; ++r){
            float zA = accA0[r] + accA1[r] + biasA;
            float zB = accB0[r] + accB1[r] + biasB;
            float oA = __shfl_xor(zA, 8);
            float oB = __shfl_xor(zB, 8);
            float zi = ga0 ? zA : oA;
            float zf = ga0 ? oA : zA;
            float zg = ga0 ? zB : oB;
            float zo = ga0 ? oB : zB;
            float cn = sigf(zf) * cst[r] + sigf(zi) * tanh_f(zg);
            float hn = sigf(zo) * tanh_f(cn);
            cst[r] = cn;
            if (ga0){
                __bf16 hh = (__bf16)hn;
                __bf16 hl = (__bf16)(hn - (float)hh);
                unsigned int pk = (((unsigned int)__builtin_bit_cast(unsigned short, hh)) << 16)
                                | (unsigned int)__builtin_bit_cast(unsigned short, hl);
                int row = bg * 16 + l4 * 4 + r;
                (void)__hip_atomic_exchange(&h_all[H_ALL(dir, s, row, dimG)], pk,
                                            __ATOMIC_RELAXED, __HIP_MEMORY_SCOPE_AGENT);
            }
        }
        // I) signal: own RMWs retired at the coherent point, then per-wave relaxed add
        asm volatile("s_waitcnt vmcnt(0)" ::: "memory");
        if (lane == 0)
            (void)__hip_atomic_fetch_add(ctr, 1u, __ATOMIC_RELAXED, __HIP_MEMORY_SCOPE_AGENT);
    }
}

// ---------------- logits = [hf|hb] @ W_out + b_out ----------------
__global__ __launch_bounds__(256) void k_logits(const unsigned int* __restrict__ h_all,
                                                const float* __restrict__ Wo, const float* __restrict__ bo,
                                                float* __restrict__ out){
    __shared__ float hs[32][513];
    __shared__ float wsm[512 * 9];
    __shared__ float bs[9];
    int tid = threadIdx.x, wgid = blockIdx.x;
    int b = wgid >> 3, t0 = (wgid & 7) * 32;
    for (int idx = tid; idx < 512 * 9; idx += 256) wsm[idx] = Wo[idx];
    if (tid < 9) bs[tid] = bo[tid];
    for (int idx = tid; idx < 32 * 512; idx += 256){
        int r = idx >> 9, k = idx & 511;
        int t = t0 + r;
        unsigned int pk = (k < HH) ? h_all[H_ALL(0, t, b, k)]
                                   : h_all[H_ALL(1, 255 - t, b, k - HH)];
        float hi = __builtin_bit_cast(float, (pk >> 16) << 16);
        float lo = __builtin_bit_cast(float, (pk & 0xffffu) << 16);
        hs[r][k] = hi + lo;
    }
    __syncthreads();
    for (int pos = tid; pos < 32 * 9; pos += 256){
        int r = pos / 9, l = pos - r * 9;
        float acc = bs[l];
        #pragma unroll 8
        for (int k = 0; k < 512; ++k)
            acc = fmaf(hs[r][k], wsm[k * 9 + l], acc);
        out[(b * 256 + t0 + r) * 9 + l] = acc;
    }
}

// ---------------- CRF: score, log-norm, viterbi, backtrace ----------------
__global__ __launch_bounds__(128) void k_crf(const float* __restrict__ logits, const int* __restrict__ labels,
                                             const float* __restrict__ trans, const int* __restrict__ lens_i,
                                             float* __restrict__ out_ll, float* __restrict__ out_tags){
    int b = blockIdx.x, tid = threadIdx.x;
    __shared__ float lg[TT * LL];
    __shared__ float tr[81];
    __shared__ unsigned char bp[255 * LL];
    __shared__ float aF[LL], aV[LL];
    __shared__ float red[2];
    __shared__ float score_s;
    __shared__ int tagb[TT];

    const float* lgg = logits + b * TT * LL;
    for (int idx = tid; idx < TT * LL; idx += 128) lg[idx] = lgg[idx];
    if (tid < 81) tr[tid] = trans[tid];
    __syncthreads();
    const int len = lens_i[b];
    const int* lab = labels + (b << 8);

    float local = 0.f;
    for (int t = tid; t < TT; t += 128){
        if (t < len){
            int lt = lab[t];
            local += lg[t * LL + lt];
            if (t >= 1) local += tr[lab[t - 1] * LL + lt];
        }
    }
    #pragma unroll
    for (int o = 32; o; o >>= 1) local += __shfl_down(local, o);
    if ((tid & 63) == 0) red[tid >> 6] = local;
    __syncthreads();
    if (tid == 0) score_s = red[0] + red[1];

    if (tid < 64){
        int col = (tid < LL) ? tid : (LL - 1);
        float a = lg[col];
        for (int t = 1; t < TT; ++t){
            float ai[LL];
            #pragma unroll
            for (int i = 0; i < LL; ++i) ai[i] = __shfl(a, i);
            float m = -1e30f;
            #pragma unroll
            for (int i = 0; i < LL; ++i) m = fmaxf(m, ai[i] + tr[i * LL + col]);
            float ssum = 0.f;
            #pragma unroll
            for (int i = 0; i < LL; ++i) ssum += __expf(ai[i] + tr[i * LL + col] - m);
            float nv = m + __logf(ssum) + lg[t * LL + col];
            if (t < len) a = nv;
        }
        if (tid < LL) aF[tid] = a;
    } else {
        int lane = tid - 64;
        int col = (lane < LL) ? lane : (LL - 1);
        float v = lg[col];
        for (int t = 1; t < TT; ++t){
            float vi[LL];
            #pragma unroll
            for (int i = 0; i < LL; ++i) vi[i] = __shfl(v, i);
            float best = -1e30f; int barg = 0;
            #pragma unroll
            for (int i = 0; i < LL; ++i){
                float sc = vi[i] + tr[i * LL + col];
                if (sc > best){ best = sc; barg = i; }
            }
            float nv = best + lg[t * LL + col];
            bool keep = (t < len);
            if (lane < LL) bp[(t - 1) * LL + lane] = (unsigned char)(keep ? barg : lane);
            if (keep) v = nv;
        }
        if (lane < LL) aV[lane] = v;
    }
    __syncthreads();

    if (tid == 0){
        float m = aF[0];
        #pragma unroll
        for (int i = 1; i < LL; ++i) m = fmaxf(m, aF[i]);
        float ssum = 0.f;
        #pragma unroll
        for (int i = 0; i < LL; ++i) ssum += __expf(aF[i] - m);
        float lognorm = m + __logf(ssum);

        float bv2 = aV[0]; int last = 0;
        #pragma unroll
        for (int i = 1; i < LL; ++i) if (aV[i] > bv2){ bv2 = aV[i]; last = i; }
        int tag = last; tagb[TT - 1] = last;
        for (int k = TT - 2; k >= 0; --k){ tag = bp[k * LL + tag]; tagb[k] = tag; }
        out_ll[b] = score_s - lognorm;
    }
    __syncthreads();
    for (int t = tid; t < TT; t += 128) out_tags[(b << 8) + t] = (float)tagb[t];
}

// ---------------- launcher ----------------
extern "C" void kernel_launch(void* const* d_in, const int* in_sizes, int n_in,
                              void* d_out, int out_size, void* d_ws, size_t ws_size,
                              hipStream_t stream){
    const int*   ch    = (const int*)  d_in[0];
    const int*   wd    = (const int*)  d_in[1];
    const int*   lab   = (const int*)  d_in[2];
    const float* cemb  = (const float*)d_in[3];
    const float* wemb  = (const float*)d_in[4];
    const float* Ww    = (const float*)d_in[5];
    const float* Wi_f  = (const float*)d_in[6];
    const float* Wh_f  = (const float*)d_in[7];
    const float* b_f   = (const float*)d_in[8];
    const float* Wi_b  = (const float*)d_in[9];
    const float* Wh_b  = (const float*)d_in[10];
    const float* b_b   = (const float*)d_in[11];
    const float* Wo    = (const float*)d_in[12];
    const float* bo    = (const float*)d_in[13];
    const float* trans = (const float*)d_in[14];

    float* out = (float*)d_out;
    float* out_logits = out;               // 64*256*9
    float* out_lens   = out + 147456;      // 64
    float* out_ll     = out + 147520;      // 64
    float* out_tags   = out + 147584;      // 64*256

    // workspace layout (total 40,898,560 B -- below round-1-proven 41,947,136 B)
    char* ws = (char*)d_ws;
    unsigned int*   ctrs   = (unsigned int*)ws;                                  // 1 KB
    int*            lens_i = (int*)(ws + 2048);                                  // 256 B
    unsigned int*   h_all  = (unsigned int*)(ws + 4096);                         // 32 MB
    unsigned short* xpack  = (unsigned short*)(ws + 4096 + 33554432);            // 4 MB
    unsigned short* Whip   = (unsigned short*)(ws + 4096 + 33554432 + 4194304);  // 1.5 MB
    unsigned short* Wlop   = (unsigned short*)(ws + 4096 + 33554432 + 4194304 + 1572864); // 1.5 MB

    hipMemsetAsync(d_ws, 0, 2048, stream);
    k_lens  <<<BB, 256, 0, stream>>>(ch, lens_i, out_lens);
    k_wpack <<<192, 256, 0, stream>>>(Wi_f, Wh_f, Wi_b, Wh_b, Whip, Wlop);
    k_x     <<<(BB * TT) / 2, 256, 0, stream>>>(ch, wd, cemb, wemb, Ww, xpack);
    k_lstm  <<<64, 256, 0, stream>>>(b_f, b_b, Whip, Wlop, xpack, h_all, ctrs);
    k_logits<<<(BB * TT) / 32, 256, 0, stream>>>(h_all, Wo, bo, out_logits);
    k_crf   <<<BB, 128, 0, stream>>>(out_logits, lab, trans, lens_i, out_ll, out_tags);
}